// Round 1
// baseline (860.287 us; speedup 1.0000x reference)
//
#include <hip/hip_runtime.h>

typedef __attribute__((ext_vector_type(8))) short short8;
typedef __attribute__((ext_vector_type(4))) float floatx4;
typedef __attribute__((ext_vector_type(2))) unsigned int uintx2;

#define MFMA(a, b, c) __builtin_amdgcn_mfma_f32_16x16x32_bf16((a), (b), (c), 0, 0, 0)

__device__ __forceinline__ unsigned short f2bf(float f) {
  unsigned int u = __builtin_bit_cast(unsigned int, f);
  u += ((u >> 16) & 1u) + 0x7fffu;
  return (unsigned short)(u >> 16);
}

__device__ __forceinline__ float softplus_f(float v) {
  float a = __builtin_fabsf(v);
  float e = __expf(-a);
  float l = __logf(1.0f + e);
  return __builtin_fmaxf(v, 0.0f) + l;
}

__device__ __forceinline__ unsigned int pack_sp(float lo, float hi) {
  return (unsigned int)f2bf(softplus_f(lo)) | ((unsigned int)f2bf(softplus_f(hi)) << 16);
}

// out[n*K + k] = bf16(in[k*N + n]); in is K x N row-major fp32
__global__ void transpose_cvt(const float* __restrict__ in, unsigned short* __restrict__ out,
                              int K, int N) {
  __shared__ float tile[32][33];
  const int bn = blockIdx.x * 32, bk = blockIdx.y * 32;
  const int tx = threadIdx.x, ty = threadIdx.y;  // 32 x 8
#pragma unroll
  for (int i = 0; i < 32; i += 8)
    tile[ty + i][tx] = in[(size_t)(bk + ty + i) * N + bn + tx];
  __syncthreads();
#pragma unroll
  for (int i = 0; i < 32; i += 8)
    out[(size_t)(bn + ty + i) * K + bk + tx] = f2bf(tile[tx][ty + i]);
}

// Fused MLP. Transposed MFMA formulation: D[n][m] = sum_k Wt[n][k] * act[m][k].
// A-frag: lane holds Wt[n = base + (l&15)][k = ks*32 + (l>>4)*8 + j], j=0..7 (16B global load)
// B-frag: lane holds act[m = mt*16 + (l&15)][same k]                        (ds_read_b128)
// D-frag: lane holds D[n = base + (l>>4)*4 + i][m = mt*16 + (l&15)], i=0..3
// LDS layouts [m][k] bf16, element-swizzled: e = (m*SE + k) ^ ((m&7)<<3)
__global__ __launch_bounds__(512, 2) void mlp3(const float* __restrict__ x,
                                               const unsigned short* __restrict__ w1t,
                                               const unsigned short* __restrict__ w2t,
                                               const unsigned short* __restrict__ w3t,
                                               float* __restrict__ out) {
  __shared__ unsigned short h1s[64 * 1024];  // 128 KB: h1[m][n1], swizzled
  __shared__ unsigned short xs[64 * 256];    // 32 KB: x[m][k] then h2 chunk [m][n2l]

  const int tid = threadIdx.x;
  const int lane = tid & 63;
  const int wv = tid >> 6;   // wave 0..7
  const int l15 = lane & 15;
  const int g = lane >> 4;   // 0..3
  const size_t m0 = (size_t)blockIdx.x * 64;

  const floatx4 z4 = {0.f, 0.f, 0.f, 0.f};

  // ---- stage x tile: 64x256 fp32 -> bf16 LDS (coalesced, swizzled) ----
  {
    const float* xp = x + m0 * 256;
#pragma unroll
    for (int r = 0; r < 8; ++r) {
      int idx4 = r * 512 + tid;     // float4 index over 64x256
      int m = idx4 >> 6;            // 64 float4 per row
      int k = (idx4 & 63) << 2;
      floatx4 v = *(const floatx4*)(xp + m * 256 + k);
      uintx2 pk;
      pk.x = (unsigned int)f2bf(v.x) | ((unsigned int)f2bf(v.y) << 16);
      pk.y = (unsigned int)f2bf(v.z) | ((unsigned int)f2bf(v.w) << 16);
      int e = (m * 256 + k) ^ ((m & 7) << 3);
      *(uintx2*)(xs + e) = pk;
    }
  }
  __syncthreads();

  // ---- G1: h1 = softplus(x @ W1), computed as D[n1][m], 4 chunks of 256 n1 ----
#pragma unroll 1
  for (int c = 0; c < 4; ++c) {
    floatx4 acc[2][4];
#pragma unroll
    for (int t = 0; t < 2; ++t)
#pragma unroll
      for (int mt = 0; mt < 4; ++mt) acc[t][mt] = z4;

    const unsigned short* p0 = w1t + (size_t)(c * 256 + wv * 32 + l15) * 256;
#pragma unroll
    for (int ks = 0; ks < 8; ++ks) {
      const int k = ks * 32 + g * 8;
      short8 a0 = *(const short8*)(p0 + k);
      short8 a1 = *(const short8*)(p0 + 16 * 256 + k);
      short8 b0 = *(const short8*)(xs + (((0 * 16 + l15) * 256 + k) ^ ((l15 & 7) << 3)));
      short8 b1 = *(const short8*)(xs + (((1 * 16 + l15) * 256 + k) ^ ((l15 & 7) << 3)));
      short8 b2 = *(const short8*)(xs + (((2 * 16 + l15) * 256 + k) ^ ((l15 & 7) << 3)));
      short8 b3 = *(const short8*)(xs + (((3 * 16 + l15) * 256 + k) ^ ((l15 & 7) << 3)));
      acc[0][0] = MFMA(a0, b0, acc[0][0]);
      acc[0][1] = MFMA(a0, b1, acc[0][1]);
      acc[0][2] = MFMA(a0, b2, acc[0][2]);
      acc[0][3] = MFMA(a0, b3, acc[0][3]);
      acc[1][0] = MFMA(a1, b0, acc[1][0]);
      acc[1][1] = MFMA(a1, b1, acc[1][1]);
      acc[1][2] = MFMA(a1, b2, acc[1][2]);
      acc[1][3] = MFMA(a1, b3, acc[1][3]);
    }
    // softplus + bf16 + write h1[m][n1] (4 consecutive n1 per lane -> b64)
#pragma unroll
    for (int t = 0; t < 2; ++t)
#pragma unroll
      for (int mt = 0; mt < 4; ++mt) {
        const int n1 = c * 256 + wv * 32 + t * 16 + g * 4;
        const int m = mt * 16 + l15;
        uintx2 pk;
        pk.x = pack_sp(acc[t][mt].x, acc[t][mt].y);
        pk.y = pack_sp(acc[t][mt].z, acc[t][mt].w);
        int e = (m * 1024 + n1) ^ ((m & 7) << 3);
        *(uintx2*)(h1s + e) = pk;
      }
  }
  __syncthreads();

  // ---- G2 + G3 fused over 4 chunks of 256 n2; acc3 persists in registers ----
  floatx4 acc3[2][4];
#pragma unroll
  for (int t = 0; t < 2; ++t)
#pragma unroll
    for (int mt = 0; mt < 4; ++mt) acc3[t][mt] = z4;

#pragma unroll 1
  for (int c2 = 0; c2 < 4; ++c2) {
    floatx4 acc2[2][4];
#pragma unroll
    for (int t = 0; t < 2; ++t)
#pragma unroll
      for (int mt = 0; mt < 4; ++mt) acc2[t][mt] = z4;

    {
      const unsigned short* p0 = w2t + (size_t)(c2 * 256 + wv * 32 + l15) * 1024;
#pragma unroll 4
      for (int ks = 0; ks < 32; ++ks) {
        const int k = ks * 32 + g * 8;
        short8 a0 = *(const short8*)(p0 + k);
        short8 a1 = *(const short8*)(p0 + 16 * 1024 + k);
        short8 b0 = *(const short8*)(h1s + (((0 * 16 + l15) * 1024 + k) ^ ((l15 & 7) << 3)));
        short8 b1 = *(const short8*)(h1s + (((1 * 16 + l15) * 1024 + k) ^ ((l15 & 7) << 3)));
        short8 b2 = *(const short8*)(h1s + (((2 * 16 + l15) * 1024 + k) ^ ((l15 & 7) << 3)));
        short8 b3 = *(const short8*)(h1s + (((3 * 16 + l15) * 1024 + k) ^ ((l15 & 7) << 3)));
        acc2[0][0] = MFMA(a0, b0, acc2[0][0]);
        acc2[0][1] = MFMA(a0, b1, acc2[0][1]);
        acc2[0][2] = MFMA(a0, b2, acc2[0][2]);
        acc2[0][3] = MFMA(a0, b3, acc2[0][3]);
        acc2[1][0] = MFMA(a1, b0, acc2[1][0]);
        acc2[1][1] = MFMA(a1, b1, acc2[1][1]);
        acc2[1][2] = MFMA(a1, b2, acc2[1][2]);
        acc2[1][3] = MFMA(a1, b3, acc2[1][3]);
      }
    }
    __syncthreads();  // prior G3 reads of xs complete before overwrite
#pragma unroll
    for (int t = 0; t < 2; ++t)
#pragma unroll
      for (int mt = 0; mt < 4; ++mt) {
        const int n2l = wv * 32 + t * 16 + g * 4;
        const int m = mt * 16 + l15;
        uintx2 pk;
        pk.x = pack_sp(acc2[t][mt].x, acc2[t][mt].y);
        pk.y = pack_sp(acc2[t][mt].z, acc2[t][mt].w);
        int e = (m * 256 + n2l) ^ ((m & 7) << 3);
        *(uintx2*)(xs + e) = pk;
      }
    __syncthreads();  // h2 chunk visible to all waves
    {
      const unsigned short* p0 = w3t + (size_t)(wv * 32 + l15) * 1024 + c2 * 256;
#pragma unroll
      for (int ks = 0; ks < 8; ++ks) {
        const int k = ks * 32 + g * 8;
        short8 a0 = *(const short8*)(p0 + k);
        short8 a1 = *(const short8*)(p0 + 16 * 1024 + k);
        short8 b0 = *(const short8*)(xs + (((0 * 16 + l15) * 256 + k) ^ ((l15 & 7) << 3)));
        short8 b1 = *(const short8*)(xs + (((1 * 16 + l15) * 256 + k) ^ ((l15 & 7) << 3)));
        short8 b2 = *(const short8*)(xs + (((2 * 16 + l15) * 256 + k) ^ ((l15 & 7) << 3)));
        short8 b3 = *(const short8*)(xs + (((3 * 16 + l15) * 256 + k) ^ ((l15 & 7) << 3)));
        acc3[0][0] = MFMA(a0, b0, acc3[0][0]);
        acc3[0][1] = MFMA(a0, b1, acc3[0][1]);
        acc3[0][2] = MFMA(a0, b2, acc3[0][2]);
        acc3[0][3] = MFMA(a0, b3, acc3[0][3]);
        acc3[1][0] = MFMA(a1, b0, acc3[1][0]);
        acc3[1][1] = MFMA(a1, b1, acc3[1][1]);
        acc3[1][2] = MFMA(a1, b2, acc3[1][2]);
        acc3[1][3] = MFMA(a1, b3, acc3[1][3]);
      }
    }
  }

  // ---- store out[m][n3] fp32: 4 consecutive n3 per lane -> dwordx4 ----
#pragma unroll
  for (int t = 0; t < 2; ++t)
#pragma unroll
    for (int mt = 0; mt < 4; ++mt) {
      const int n3 = wv * 32 + t * 16 + g * 4;
      const int m = mt * 16 + l15;
      *(floatx4*)(out + (m0 + m) * 256 + n3) = acc3[t][mt];
    }
}

extern "C" void kernel_launch(void* const* d_in, const int* in_sizes, int n_in,
                              void* d_out, int out_size, void* d_ws, size_t ws_size,
                              hipStream_t stream) {
  const float* x = (const float*)d_in[0];
  const float* w1 = (const float*)d_in[1];
  const float* w2 = (const float*)d_in[2];
  const float* w3 = (const float*)d_in[3];
  float* out = (float*)d_out;

  unsigned short* w1t = (unsigned short*)d_ws;            // [1024][256]  bf16, 512 KB
  unsigned short* w2t = w1t + 1024 * 256;                 // [1024][1024] bf16, 2 MB
  unsigned short* w3t = w2t + 1024 * 1024;                // [256][1024]  bf16, 512 KB

  dim3 tb(32, 8);
  transpose_cvt<<<dim3(1024 / 32, 256 / 32), tb, 0, stream>>>(w1, w1t, 256, 1024);
  transpose_cvt<<<dim3(1024 / 32, 1024 / 32), tb, 0, stream>>>(w2, w2t, 1024, 1024);
  transpose_cvt<<<dim3(256 / 32, 1024 / 32), tb, 0, stream>>>(w3, w3t, 1024, 256);

  mlp3<<<131072 / 64, 512, 0, stream>>>(x, w1t, w2t, w3t, out);
}